// Round 1
// baseline (104.262 us; speedup 1.0000x reference)
//
#include <hip/hip_runtime.h>

#define NN 8192
#define TILE 256
#define ALPHA_C 3.0f
#define MIN_DIFF_C 0.1f

// ws layout: [0] float pair_sum, [1] uint cnt, [2] float reg_sum
__global__ __launch_bounds__(TILE) void pair_kernel(
    const float* __restrict__ pred, const float* __restrict__ targ,
    float* __restrict__ pair_sum, unsigned int* __restrict__ cnt,
    float* __restrict__ reg_sum) {
    const int ti = blockIdx.y;   // i-tile
    const int tj = blockIdx.x;   // j-tile
    if (ti > tj) return;         // upper-triangular tiles only (uniform exit)

    __shared__ float sp[TILE];
    __shared__ float st[TILE];
    const int tid = threadIdx.x;
    const int i0 = ti * TILE;
    const int j0 = tj * TILE;

    sp[tid] = pred[i0 + tid];
    st[tid] = targ[i0 + tid];
    __syncthreads();

    const int j = j0 + tid;
    const float pj = pred[j];
    const float tjv = targ[j];

    float s = 0.0f;   // masked pairwise loss sum
    int   c = 0;      // masked pair count
    float r = 0.0f;   // regression contribution (diagonal blocks only)

    if (ti < tj) {
        // full tile: every (i,j) has i < j
        #pragma unroll 4
        for (int ii = 0; ii < TILE; ++ii) {
            const float dt   = st[ii] - tjv;
            const float conf = fabsf(dt);
            const bool  valid = conf > MIN_DIFF_C;
            const float x = (sp[ii] - pj) * (dt > 0.0f ? 1.0f : -1.0f);
            // -log_sigmoid(x) = max(-x,0) + log(1+exp(-|x|))
            const float l = fmaxf(-x, 0.0f) + __logf(1.0f + __expf(-fabsf(x)));
            s += valid ? conf * l : 0.0f;
            c += valid ? 1 : 0;
        }
    } else {
        // diagonal tile: predicate on i < j
        #pragma unroll 4
        for (int ii = 0; ii < TILE; ++ii) {
            const int i = i0 + ii;
            const float dt   = st[ii] - tjv;
            const float conf = fabsf(dt);
            const bool  valid = (i < j) && (conf > MIN_DIFF_C);
            const float x = (sp[ii] - pj) * (dt > 0.0f ? 1.0f : -1.0f);
            const float l = fmaxf(-x, 0.0f) + __logf(1.0f + __expf(-fabsf(x)));
            s += valid ? conf * l : 0.0f;
            c += valid ? 1 : 0;
        }
        // each global j appears in exactly one diagonal block -> MSE term
        const float d = pj - tjv;
        r = d * d;
    }

    // ---- block reduction: wave shuffle (64 lanes) then LDS across 4 waves ----
    #pragma unroll
    for (int off = 32; off > 0; off >>= 1) {
        s += __shfl_down(s, off, 64);
        c += __shfl_down(c, off, 64);
        r += __shfl_down(r, off, 64);
    }
    __shared__ float ws_s[4];
    __shared__ int   ws_c[4];
    __shared__ float ws_r[4];
    const int wave = tid >> 6;
    const int lane = tid & 63;
    if (lane == 0) { ws_s[wave] = s; ws_c[wave] = c; ws_r[wave] = r; }
    __syncthreads();
    if (tid == 0) {
        float fs = ws_s[0] + ws_s[1] + ws_s[2] + ws_s[3];
        int   fc = ws_c[0] + ws_c[1] + ws_c[2] + ws_c[3];
        float fr = ws_r[0] + ws_r[1] + ws_r[2] + ws_r[3];
        atomicAdd(pair_sum, fs);
        atomicAdd(cnt, (unsigned int)fc);
        if (ti == tj) atomicAdd(reg_sum, fr);
    }
}

__global__ void finalize_kernel(const float* __restrict__ pair_sum,
                                const unsigned int* __restrict__ cnt,
                                const float* __restrict__ reg_sum,
                                float* __restrict__ out) {
    const float reg = reg_sum[0] / (float)NN;
    const unsigned int c = cnt[0];
    const float pm = (c > 0) ? (pair_sum[0] / (float)c) : 0.0f;
    out[0] = (c > 0) ? (reg + ALPHA_C * pm) : reg;
}

extern "C" void kernel_launch(void* const* d_in, const int* in_sizes, int n_in,
                              void* d_out, int out_size, void* d_ws, size_t ws_size,
                              hipStream_t stream) {
    const float* pred = (const float*)d_in[0];
    const float* targ = (const float*)d_in[1];
    float* out = (float*)d_out;

    float*        pair_sum = (float*)d_ws;
    unsigned int* cnt      = (unsigned int*)((char*)d_ws + 4);
    float*        reg_sum  = (float*)((char*)d_ws + 8);

    // ws is poisoned to 0xAA before every timed launch — zero our accumulators
    hipMemsetAsync(d_ws, 0, 16, stream);

    dim3 grid(NN / TILE, NN / TILE);  // 32 x 32; lower-triangular blocks exit
    pair_kernel<<<grid, TILE, 0, stream>>>(pred, targ, pair_sum, cnt, reg_sum);
    finalize_kernel<<<1, 1, 0, stream>>>(pair_sum, cnt, reg_sum, out);
}

// Round 2
// 86.080 us; speedup vs baseline: 1.2112x; 1.2112x over previous
//
#include <hip/hip_runtime.h>
#include <math.h>

#define NN 8192
#define TS 128                       // tile side
#define NT (NN / TS)                 // 64 tiles per dim
#define NTILES ((NT * (NT + 1)) / 2) // 2080 upper-tri tiles (incl. diagonal)
#define BLOCK 256
#define ALPHA_C 3.0f
#define MIN_DIFF_C 0.1f

// Each block owns one 128x128 (i,j) tile, ti <= tj. 256 threads: thread t
// handles j = tj*128 + (t & 127); the two halves (t>>7) split the i-range.
// Partials (pair_sum, count, reg_sum) go to ws[b] as float4 — no atomics,
// no memset (every block writes its slot).
__global__ __launch_bounds__(BLOCK, 8) void pair_kernel(
    const float* __restrict__ pred, const float* __restrict__ targ,
    float4* __restrict__ parts) {
    // ---- decode linear tile id -> (ti, tj), row-major upper triangle ----
    const int b = blockIdx.x;
    int ti = (int)((2.0 * NT + 1.0 -
                    sqrt((2.0 * NT + 1.0) * (2.0 * NT + 1.0) - 8.0 * (double)b)) * 0.5);
    int start = ti * NT - (ti * (ti - 1)) / 2;
    if (b < start) { --ti; start = ti * NT - (ti * (ti - 1)) / 2; }
    else if (b >= start + (NT - ti)) { start += NT - ti; ++ti; }
    const int tj = ti + (b - start);

    __shared__ float2 sT[TS];        // (pred_i, targ_i) for the i-tile
    const int tid  = threadIdx.x;
    const int jl   = tid & (TS - 1);
    const int half = tid >> 7;       // 0 or 1: which half of the i-range
    const int i0   = ti * TS;
    const int j    = tj * TS + jl;

    if (tid < TS) sT[tid] = make_float2(pred[i0 + tid], targ[i0 + tid]);
    __syncthreads();

    const float pj  = pred[j];
    const float tjv = targ[j];

    float s = 0.0f;  // masked pairwise-loss sum
    float c = 0.0f;  // masked pair count (exact: <= 8192 per thread)
    float r = 0.0f;  // regression contribution (diagonal blocks, half 0 only)

    const int ib = half * (TS / 2);
    const int ie = ib + (TS / 2);

    if (ti < tj) {
        #pragma unroll 8
        for (int ii = ib; ii < ie; ++ii) {
            const float2 v  = sT[ii];
            const float dt  = v.y - tjv;
            const float dp  = v.x - pj;
            const bool valid = fabsf(dt) > MIN_DIFF_C;
            // x = dp * sign(dt): flip dp's sign bit by dt's sign bit
            const unsigned sb = __float_as_uint(dt) & 0x80000000u;
            const float x   = __uint_as_float(__float_as_uint(dp) ^ sb);
            const float nax = __uint_as_float(__float_as_uint(x) | 0x80000000u); // -|x|
            // -log_sigmoid(x) = max(-x,0) + log(1+exp(-|x|))
            const float l = fmaxf(-x, 0.0f) + __logf(1.0f + __expf(nax));
            const float cm = valid ? fabsf(dt) : 0.0f;
            s = fmaf(cm, l, s);
            c += valid ? 1.0f : 0.0f;
        }
    } else {
        // diagonal tile: predicate on global i < j
        #pragma unroll 4
        for (int ii = ib; ii < ie; ++ii) {
            const float2 v  = sT[ii];
            const int   i   = i0 + ii;
            const float dt  = v.y - tjv;
            const float dp  = v.x - pj;
            const bool valid = (i < j) && (fabsf(dt) > MIN_DIFF_C);
            const unsigned sb = __float_as_uint(dt) & 0x80000000u;
            const float x   = __uint_as_float(__float_as_uint(dp) ^ sb);
            const float nax = __uint_as_float(__float_as_uint(x) | 0x80000000u);
            const float l = fmaxf(-x, 0.0f) + __logf(1.0f + __expf(nax));
            const float cm = valid ? fabsf(dt) : 0.0f;
            s = fmaf(cm, l, s);
            c += valid ? 1.0f : 0.0f;
        }
        if (half == 0) { const float d = pj - tjv; r = d * d; }
    }

    // ---- block reduction: wave shuffle (64) then LDS across 4 waves ----
    #pragma unroll
    for (int off = 32; off > 0; off >>= 1) {
        s += __shfl_down(s, off, 64);
        c += __shfl_down(c, off, 64);
        r += __shfl_down(r, off, 64);
    }
    __shared__ float red_s[4], red_c[4], red_r[4];
    const int wave = tid >> 6;
    const int lane = tid & 63;
    if (lane == 0) { red_s[wave] = s; red_c[wave] = c; red_r[wave] = r; }
    __syncthreads();
    if (tid == 0) {
        parts[b] = make_float4(red_s[0] + red_s[1] + red_s[2] + red_s[3],
                               red_c[0] + red_c[1] + red_c[2] + red_c[3],
                               red_r[0] + red_r[1] + red_r[2] + red_r[3], 0.0f);
    }
}

__global__ __launch_bounds__(256) void finalize_kernel(
    const float4* __restrict__ parts, float* __restrict__ out) {
    float s = 0.0f, c = 0.0f, r = 0.0f;
    for (int t = threadIdx.x; t < NTILES; t += 256) {
        const float4 v = parts[t];
        s += v.x; c += v.y; r += v.z;
    }
    #pragma unroll
    for (int off = 32; off > 0; off >>= 1) {
        s += __shfl_down(s, off, 64);
        c += __shfl_down(c, off, 64);
        r += __shfl_down(r, off, 64);
    }
    __shared__ float red_s[4], red_c[4], red_r[4];
    const int wave = threadIdx.x >> 6;
    const int lane = threadIdx.x & 63;
    if (lane == 0) { red_s[wave] = s; red_c[wave] = c; red_r[wave] = r; }
    __syncthreads();
    if (threadIdx.x == 0) {
        const float fs = red_s[0] + red_s[1] + red_s[2] + red_s[3];
        const float fc = red_c[0] + red_c[1] + red_c[2] + red_c[3];
        const float fr = red_r[0] + red_r[1] + red_r[2] + red_r[3];
        const float reg = fr / (float)NN;
        out[0] = (fc > 0.0f) ? (reg + ALPHA_C * (fs / fmaxf(fc, 1.0f))) : reg;
    }
}

extern "C" void kernel_launch(void* const* d_in, const int* in_sizes, int n_in,
                              void* d_out, int out_size, void* d_ws, size_t ws_size,
                              hipStream_t stream) {
    const float* pred = (const float*)d_in[0];
    const float* targ = (const float*)d_in[1];
    float* out = (float*)d_out;
    float4* parts = (float4*)d_ws;   // NTILES * 16 B = 33,280 B

    pair_kernel<<<NTILES, BLOCK, 0, stream>>>(pred, targ, parts);
    finalize_kernel<<<1, 256, 0, stream>>>(parts, out);
}